// Round 4
// baseline (1160.698 us; speedup 1.0000x reference)
//
#include <hip/hip_runtime.h>
#include <hip/hip_bf16.h>
#include <math.h>

#define NN 15000
#define NE 60000
#define NB 512
#define NIF 15
#define EIF 5
#define EHID 128
#define NSTEP 6
#define EPB 128   // edges per k_msg block (2 waves x 64)

typedef _Float16 half8 __attribute__((ext_vector_type(8)));
typedef _Float16 half4v __attribute__((ext_vector_type(4)));
typedef float floatx4 __attribute__((ext_vector_type(4)));

__device__ __forceinline__ float sigmoidf_(float x) { return 1.f / (1.f + expf(-x)); }

__global__ void k_sentinel(float* out) { out[0] = 1000.0f; }

// ---- fused setup: lin0 (+relu), degree, per-graph bounds ----
__global__ void k_setup(const float* __restrict__ x, const float* __restrict__ l0w,
                        const float* __restrict__ l0b, const int* __restrict__ tgt,
                        const int* __restrict__ batch, float* __restrict__ outv,
                        float* __restrict__ deg, int* __restrict__ gstart,
                        int* __restrict__ gend) {
  int idx = blockIdx.x * 256 + threadIdx.x;
  if (idx < NN * 64) {
    int n = idx >> 6, d = idx & 63;
    float s = l0b[d];
#pragma unroll
    for (int i = 0; i < NIF; ++i) s += x[n * NIF + i] * l0w[d * NIF + i];
    outv[idx] = fmaxf(s, 0.f);
  }
  if (idx < NE) atomicAdd(&deg[tgt[idx]], 1.0f);
  if (idx < NN) {
    int bb = batch[idx];
    atomicMin(&gstart[bb], idx);
    atomicMax(&gend[bb], idx + 1);
  }
}

// ---- fused pack: w2pp (edge-net B-frags), gru wgpk (B-frags), lstm transposed ----
// w2pp: idx<528384, layout [g<1032][o<64][j<8]; g<1024: k=g*8+j, i=k>>7, h=k&127,
//       val=w2[(i*64+o)*128+h]; g>=1024: i=(g-1024)*8+j, val=b2[i*64+o].
__global__ void k_packall(const float* __restrict__ w2, const float* __restrict__ b2,
                          const float* __restrict__ gwih, const float* __restrict__ gwhh,
                          const float* __restrict__ lwih, const float* __restrict__ lwhh,
                          _Float16* __restrict__ w2pp, _Float16* __restrict__ wgpk,
                          float* __restrict__ wTih, float* __restrict__ wThh) {
  int idx = blockIdx.x * 256 + threadIdx.x;
  if (idx < 528384) {
    int g = idx >> 9;
    int r = idx & 511;
    int o = r >> 3, j = r & 7;
    float v;
    if (g < 1024) {
      int i = g >> 4;
      int h = ((g & 15) << 3) + j;
      v = w2[(size_t)(i * 64 + o) * 128 + h];
    } else {
      int i = ((g - 1024) << 3) + j;
      v = b2[i * 64 + o];
    }
    w2pp[idx] = (_Float16)v;
  } else if (idx < 528384 + 24576) {
    int i2 = idx - 528384;
    int kc = i2 / 6144;
    int rem = i2 % 6144;
    int o = rem >> 5, r = rem & 31;
    int kind = kc >> 1, cc = kc & 1;
    float v = kind ? gwhh[o * 64 + cc * 32 + r] : gwih[o * 64 + cc * 32 + r];
    wgpk[i2] = (_Float16)v;
  } else if (idx < 528384 + 24576 + 32768) {
    int i3 = idx - (528384 + 24576);
    int k = i3 >> 8, g = i3 & 255;
    wTih[i3] = lwih[g * 128 + k];
  } else if (idx < 528384 + 24576 + 32768 + 16384) {
    int i4 = idx - (528384 + 24576 + 32768);
    int k = i4 >> 8, g = i4 & 255;
    wThh[i4] = lwhh[g * 64 + k];
  }
}

// ---- fused message pass, 8-way K-split, B double-buffered ----
// blockIdx.y = split sy in [0,8): ib=sy>>2 (i-range 32), hb=sy&3 (h-range 32).
// K-chunks c = (ib*32+il)*4 + hb, il<32; bias chunk 256+ib on hb==0 blocks.
// hid A-frags loop-invariant (1 half8 per m-tile). B-frags prefetched 1 chunk ahead;
// first chunk's B load hoisted above the hid prologue (L2 latency overlap).
__global__ __launch_bounds__(128, 4) void k_msg(
    const float* __restrict__ outv, const float* __restrict__ ea,
    const float* __restrict__ w1, const float* __restrict__ b1,
    const _Float16* __restrict__ w2pp, const int* __restrict__ src,
    const int* __restrict__ tgt, float* __restrict__ agg) {
  __shared__ __align__(16) _Float16 hidL[EPB][40];  // h-range 32 + pad8 (80B rows)
  __shared__ __align__(16) _Float16 osL[EPB][40];   // i-range 32 + pad8
  __shared__ float w1L[192];                        // 32x5 w1 + 32 b1 (h-range)
  int tid = threadIdx.x;
  int e0 = blockIdx.x * EPB;
  int ib = blockIdx.y >> 2, hb = blockIdx.y & 3;
  int wv = tid >> 6, lane = tid & 63;
  int l15 = lane & 15, q = lane >> 4;

  // B-frag base for this lane: w2pp index = c*2048 + q*512 + l15*8 (+og*128)
  const _Float16* bbase = w2pp + (size_t)q * 512 + (size_t)l15 * 8;
  half8 bf[2][4];
  {  // prefetch chunk t=0 before any LDS work
    size_t c0 = (size_t)((ib * 32 + 0) * 4 + hb) * 2048;
#pragma unroll
    for (int og = 0; og < 4; ++og)
      bf[0][og] = *(const half8*)(bbase + c0 + og * 128);
  }

  for (int idx = tid; idx < 192; idx += EPB)
    w1L[idx] = (idx < 160) ? w1[hb * 160 + idx] : b1[hb * 32 + idx - 160];

  int e = e0 + tid;
  bool valid = e < NE;
  int s = valid ? src[e] : 0;
  const float4* op = (const float4*)(outv + (size_t)s * 64 + ib * 32);
#pragma unroll
  for (int qq = 0; qq < 8; ++qq) {
    float4 v = op[qq];
    if (!valid) v = make_float4(0.f, 0.f, 0.f, 0.f);
    osL[tid][qq * 4 + 0] = (_Float16)v.x;
    osL[tid][qq * 4 + 1] = (_Float16)v.y;
    osL[tid][qq * 4 + 2] = (_Float16)v.z;
    osL[tid][qq * 4 + 3] = (_Float16)v.w;
  }
  float eav[EIF];
#pragma unroll
  for (int i = 0; i < EIF; ++i) eav[i] = valid ? ea[e * EIF + i] : 0.f;
  __syncthreads();  // w1L ready
  for (int hh = 0; hh < 32; ++hh) {
    float sum = w1L[160 + hh];
#pragma unroll
    for (int i = 0; i < EIF; ++i) sum += eav[i] * w1L[hh * EIF + i];
    hidL[tid][hh] = (_Float16)fmaxf(sum, 0.f);
  }
  __syncthreads();

  int rbase = wv * 64 + l15;
  half8 hidf[4];  // loop-invariant A h-factors
#pragma unroll
  for (int m = 0; m < 4; ++m)
    hidf[m] = *(const half8*)&hidL[rbase + m * 16][q * 8];

  floatx4 acc[4][4];
#pragma unroll
  for (int m = 0; m < 4; ++m)
#pragma unroll
    for (int og = 0; og < 4; ++og) acc[m][og] = (floatx4){0.f, 0.f, 0.f, 0.f};

  for (int il4 = 0; il4 < 8; ++il4) {
    half4v os4[4];
#pragma unroll
    for (int m = 0; m < 4; ++m)
      os4[m] = *(const half4v*)&osL[rbase + m * 16][il4 * 4];  // ds_read_b64
#pragma unroll
    for (int u = 0; u < 4; ++u) {
      int t = il4 * 4 + u;
      int cur = t & 1, nxt = cur ^ 1;
      if (t < 31) {  // prefetch next chunk's B
        size_t cn = (size_t)((ib * 32 + t + 1) * 4 + hb) * 2048;
#pragma unroll
        for (int og = 0; og < 4; ++og)
          bf[nxt][og] = *(const half8*)(bbase + cn + og * 128);
      } else if (hb == 0) {  // prefetch bias chunk
        size_t cn = (size_t)(256 + ib) * 2048;
#pragma unroll
        for (int og = 0; og < 4; ++og)
          bf[nxt][og] = *(const half8*)(bbase + cn + og * 128);
      }
      half8 af[4];
#pragma unroll
      for (int m = 0; m < 4; ++m) {
        _Float16 ov = os4[m][u];
        half8 osp = {ov, ov, ov, ov, ov, ov, ov, ov};
        af[m] = hidf[m] * osp;
      }
#pragma unroll
      for (int og = 0; og < 4; ++og)
#pragma unroll
        for (int m = 0; m < 4; ++m)
          acc[m][og] = __builtin_amdgcn_mfma_f32_16x16x32_f16(af[m], bf[cur][og], acc[m][og], 0, 0, 0);
    }
  }

  if (hb == 0) {  // bias chunk (t=32, parity 0): A = os directly
    half8 af[4];
#pragma unroll
    for (int m = 0; m < 4; ++m)
      af[m] = *(const half8*)&osL[rbase + m * 16][q * 8];
#pragma unroll
    for (int og = 0; og < 4; ++og)
#pragma unroll
      for (int m = 0; m < 4; ++m)
        acc[m][og] = __builtin_amdgcn_mfma_f32_16x16x32_f16(af[m], bf[0][og], acc[m][og], 0, 0, 0);
  }

  // epilogue: C/D row=(lane>>4)*4+j (edge), col=lane&15
#pragma unroll
  for (int m = 0; m < 4; ++m) {
    int erow = e0 + wv * 64 + m * 16 + q * 4;
#pragma unroll
    for (int j = 0; j < 4; ++j) {
      int ee = erow + j;
      if (ee < NE) {
        int t = tgt[ee];
        float* ap = agg + (size_t)t * 64 + l15;
#pragma unroll
        for (int og = 0; og < 4; ++og) atomicAdd(ap + og * 16, acc[m][og][j]);
      }
    }
  }
}

// ---- GRU step via MFMA; zeroes agg in-place for next step's atomics ----
__global__ __launch_bounds__(256, 2) void k_gru(
    float* __restrict__ agg, const float* __restrict__ deg,
    const float* __restrict__ convb, const _Float16* __restrict__ wgpk,
    const float* __restrict__ bih, const float* __restrict__ bhh,
    float* __restrict__ outv) {
  __shared__ __align__(16) _Float16 aL[64][136];  // K=128 + pad8
  __shared__ float hF[64][68];
  __shared__ float cbL[64];
  int tid = threadIdx.x;
  int n0 = blockIdx.x * 64;
  if (tid < 64) cbL[tid] = convb[tid];
  __syncthreads();

  int nl = tid >> 2, dq = (tid & 3) * 16;
  int n = n0 + nl;
  if (n < NN) {
    float dg = fmaxf(deg[n], 1.f);
    const float4* ap = (const float4*)(agg + (size_t)n * 64 + dq);
    const float4* hp = (const float4*)(outv + (size_t)n * 64 + dq);
    float4* az = (float4*)(agg + (size_t)n * 64 + dq);
#pragma unroll
    for (int t = 0; t < 4; ++t) {
      float4 a = ap[t];
      float4 h = hp[t];
      int d = dq + t * 4;
      aL[nl][d + 0] = (_Float16)fmaxf(a.x / dg + cbL[d + 0], 0.f);
      aL[nl][d + 1] = (_Float16)fmaxf(a.y / dg + cbL[d + 1], 0.f);
      aL[nl][d + 2] = (_Float16)fmaxf(a.z / dg + cbL[d + 2], 0.f);
      aL[nl][d + 3] = (_Float16)fmaxf(a.w / dg + cbL[d + 3], 0.f);
      aL[nl][64 + d + 0] = (_Float16)h.x;
      aL[nl][64 + d + 1] = (_Float16)h.y;
      aL[nl][64 + d + 2] = (_Float16)h.z;
      aL[nl][64 + d + 3] = (_Float16)h.w;
      hF[nl][d + 0] = h.x; hF[nl][d + 1] = h.y;
      hF[nl][d + 2] = h.z; hF[nl][d + 3] = h.w;
      az[t] = make_float4(0.f, 0.f, 0.f, 0.f);
    }
  } else {
#pragma unroll
    for (int t = 0; t < 4; ++t) {
      int d = dq + t * 4;
#pragma unroll
      for (int u = 0; u < 4; ++u) {
        aL[nl][d + u] = (_Float16)0.f;
        aL[nl][64 + d + u] = (_Float16)0.f;
        hF[nl][d + u] = 0.f;
      }
    }
  }
  __syncthreads();

  int wv = tid >> 6, lane = tid & 63, l15 = lane & 15, qd = lane >> 4;
  floatx4 acc[4][3][2];
#pragma unroll
  for (int mt = 0; mt < 4; ++mt)
#pragma unroll
    for (int tt = 0; tt < 3; ++tt)
#pragma unroll
      for (int kind = 0; kind < 2; ++kind) acc[mt][tt][kind] = (floatx4){0.f, 0.f, 0.f, 0.f};

#pragma unroll
  for (int kind = 0; kind < 2; ++kind) {
#pragma unroll
    for (int cc = 0; cc < 2; ++cc) {
      half8 af[4];
#pragma unroll
      for (int mt = 0; mt < 4; ++mt)
        af[mt] = *(const half8*)&aL[mt * 16 + l15][kind * 64 + cc * 32 + qd * 8];
#pragma unroll
      for (int tt = 0; tt < 3; ++tt) {
        int gb = (tt * 4 + wv) * 16;
        half8 bf = *(const half8*)&wgpk[((size_t)(kind * 2 + cc) * 192 + gb + l15) * 32 + qd * 8];
#pragma unroll
        for (int mt = 0; mt < 4; ++mt)
          acc[mt][tt][kind] = __builtin_amdgcn_mfma_f32_16x16x32_f16(af[mt], bf, acc[mt][tt][kind], 0, 0, 0);
      }
    }
  }

  int d = wv * 16 + l15;
  float bir = bih[d], bhr = bhh[d];
  float biz = bih[64 + d], bhz = bhh[64 + d];
  float bin = bih[128 + d], bhn = bhh[128 + d];
#pragma unroll
  for (int mt = 0; mt < 4; ++mt) {
#pragma unroll
    for (int j = 0; j < 4; ++j) {
      int nloc = mt * 16 + qd * 4 + j;
      int nn = n0 + nloc;
      if (nn < NN) {
        float ir = acc[mt][0][0][j] + bir, hr = acc[mt][0][1][j] + bhr;
        float iz = acc[mt][1][0][j] + biz, hz = acc[mt][1][1][j] + bhz;
        float in_ = acc[mt][2][0][j] + bin, hn = acc[mt][2][1][j] + bhn;
        float r = sigmoidf_(ir + hr);
        float z = sigmoidf_(iz + hz);
        float ng = tanhf(in_ + r * hn);
        float h = hF[nloc][d];
        outv[(size_t)nn * 64 + d] = (1.f - z) * ng + z * h;
      }
    }
  }
}

// ---- fully fused Set2Set (6 steps) + head, one block per graph ----
__global__ __launch_bounds__(256) void k_s2s(
    const float* __restrict__ outv, const int* __restrict__ gstart,
    const int* __restrict__ gend, const float* __restrict__ wTih,
    const float* __restrict__ wThh, const float* __restrict__ bih,
    const float* __restrict__ bhh, const float* __restrict__ l1w,
    const float* __restrict__ l1b, const float* __restrict__ l2w,
    const float* __restrict__ l2b, float* __restrict__ y) {
  __shared__ float qL[128], hlL[64], clL[64], gL[256];
  __shared__ float mxA[4], smA[4], accA[4][64], hidL[64];
  int b = blockIdx.x, tid = threadIdx.x, wv = tid >> 6, lane = tid & 63;
  int s0 = gstart[b], e0 = gend[b];
  if (s0 > e0) { s0 = 0; e0 = 0; }
  if (tid < 128) qL[tid] = 0.f;
  if (tid < 64) { hlL[tid] = 0.f; clL[tid] = 0.f; }
  __syncthreads();

  for (int step = 0; step < NSTEP; ++step) {
    {
      int g = tid;
      float s = bih[g] + bhh[g];
      for (int k = 0; k < 128; ++k) s += qL[k] * wTih[k * 256 + g];
      for (int k = 0; k < 64; ++k) s += hlL[k] * wThh[k * 256 + g];
      gL[g] = s;
    }
    __syncthreads();
    if (tid < 64) {
      float ig = gL[tid], fg = gL[64 + tid], gg = gL[128 + tid], og = gL[192 + tid];
      float c = sigmoidf_(fg) * clL[tid] + sigmoidf_(ig) * tanhf(gg);
      clL[tid] = c;
      hlL[tid] = sigmoidf_(og) * tanhf(c);
    }
    __syncthreads();
    float hd = hlL[lane];
    float mxw = -1e30f;
    for (int nn = s0 + wv; nn < e0; nn += 4) {
      float v = outv[(size_t)nn * 64 + lane] * hd;
#pragma unroll
      for (int off = 32; off > 0; off >>= 1) v += __shfl_xor(v, off);
      mxw = fmaxf(mxw, v);
    }
    if (lane == 0) mxA[wv] = mxw;
    __syncthreads();
    float mx = fmaxf(fmaxf(mxA[0], mxA[1]), fmaxf(mxA[2], mxA[3]));
    float sm = 0.f, ac = 0.f;
    for (int nn = s0 + wv; nn < e0; nn += 4) {
      float o_nd = outv[(size_t)nn * 64 + lane];
      float v = o_nd * hd;
#pragma unroll
      for (int off = 32; off > 0; off >>= 1) v += __shfl_xor(v, off);
      float ex = expf(v - mx);
      sm += ex;
      ac += ex * o_nd;
    }
    if (lane == 0) smA[wv] = sm;
    accA[wv][lane] = ac;
    __syncthreads();
    if (tid < 64) {
      float den = smA[0] + smA[1] + smA[2] + smA[3] + 1e-16f;
      float rv = (accA[0][tid] + accA[1][tid] + accA[2][tid] + accA[3][tid]) / den;
      qL[tid] = hlL[tid];
      qL[64 + tid] = rv;
    }
    __syncthreads();
  }
  if (tid < 64) {
    float s = l1b[tid];
    for (int k = 0; k < 128; ++k) s += qL[k] * l1w[tid * 128 + k];
    hidL[tid] = fmaxf(s, 0.f);
  }
  __syncthreads();
  if (tid < 12) {
    float s = l2b[tid];
    for (int k = 0; k < 64; ++k) s += hidL[k] * l2w[tid * 64 + k];
    y[b * 12 + tid] = s;
  }
}

extern "C" void kernel_launch(void* const* d_in, const int* in_sizes, int n_in,
                              void* d_out, int out_size, void* d_ws, size_t ws_size,
                              hipStream_t stream) {
  const float* x = (const float*)d_in[0];
  const float* ea = (const float*)d_in[1];
  const int* eidx = (const int*)d_in[2];
  const int* batch = (const int*)d_in[3];
  const float* lin0_w = (const float*)d_in[4];
  const float* lin0_b = (const float*)d_in[5];
  const float* en_w1 = (const float*)d_in[6];
  const float* en_b1 = (const float*)d_in[7];
  const float* en_w2 = (const float*)d_in[8];
  const float* en_b2 = (const float*)d_in[9];
  const float* conv_b = (const float*)d_in[10];
  const float* gru_wih = (const float*)d_in[11];
  const float* gru_whh = (const float*)d_in[12];
  const float* gru_bih = (const float*)d_in[13];
  const float* gru_bhh = (const float*)d_in[14];
  const float* lstm_wih = (const float*)d_in[15];
  const float* lstm_whh = (const float*)d_in[16];
  const float* lstm_bih = (const float*)d_in[17];
  const float* lstm_bhh = (const float*)d_in[18];
  const float* lin1_w = (const float*)d_in[19];
  const float* lin1_b = (const float*)d_in[20];
  const float* lin2_w = (const float*)d_in[21];
  const float* lin2_b = (const float*)d_in[22];
  const int* srcp = eidx;
  const int* tgtp = eidx + NE;

  char* ws = (char*)d_ws;
  size_t off = 0;
  auto alloc = [&](size_t bytes) {
    char* p = ws + off;
    off += (bytes + 255) & ~(size_t)255;
    return p;
  };
  _Float16* w2pp = (_Float16*)alloc((size_t)1032 * 512 * 2);  // 1.06 MB
  _Float16* wgpk = (_Float16*)alloc((size_t)24576 * 2);
  float* wTih = (float*)alloc((size_t)32768 * 4);
  float* wThh = (float*)alloc((size_t)16384 * 4);
  float* out = (float*)alloc((size_t)NN * 64 * 4);
  float* agg = (float*)alloc((size_t)NN * 64 * 4);
  float* deg = (float*)alloc((size_t)NN * 4);
  int* gstart = (int*)alloc((size_t)NB * 4);
  int* gend = (int*)alloc((size_t)NB * 4);
  if (off > ws_size) {
    k_sentinel<<<1, 1, 0, stream>>>((float*)d_out);
    return;
  }

  hipMemsetAsync(deg, 0, (size_t)NN * 4, stream);
  hipMemsetAsync(gstart, 0x7f, (size_t)NB * 4, stream);
  hipMemsetAsync(gend, 0, (size_t)NB * 4, stream);
  hipMemsetAsync(agg, 0, (size_t)NN * 64 * 4, stream);

  k_setup<<<(NN * 64 + 255) / 256, 256, 0, stream>>>(x, lin0_w, lin0_b, tgtp, batch,
                                                     out, deg, gstart, gend);
  k_packall<<<(528384 + 24576 + 32768 + 16384 + 255) / 256, 256, 0, stream>>>(
      en_w2, en_b2, gru_wih, gru_whh, lstm_wih, lstm_whh, w2pp, wgpk, wTih, wThh);

  for (int step = 0; step < NSTEP; ++step) {
    k_msg<<<dim3((NE + EPB - 1) / EPB, 8), EPB, 0, stream>>>(out, ea, en_w1, en_b1,
                                                             w2pp, srcp, tgtp, agg);
    k_gru<<<(NN + 63) / 64, 256, 0, stream>>>(agg, deg, conv_b, wgpk, gru_bih,
                                              gru_bhh, out);
  }

  k_s2s<<<NB, 256, 0, stream>>>(out, gstart, gend, wTih, wThh, lstm_bih, lstm_bhh,
                                lin1_w, lin1_b, lin2_w, lin2_b, (float*)d_out);
}